// Round 2
// baseline (1451.752 us; speedup 1.0000x reference)
//
#include <hip/hip_runtime.h>

#define BB 32
#define DD 400
#define KK 200
#define NN (BB*KK)

__device__ __forceinline__ float fast_sigmoid(float x) {
  float e = __builtin_amdgcn_exp2f(-1.4426950408889634f * x);
  return __builtin_amdgcn_rcpf(1.0f + e);
}
__device__ __forceinline__ float fast_tanh(float x) {
  float e = __builtin_amdgcn_exp2f(-2.8853900817779268f * x);
  return 2.0f * __builtin_amdgcn_rcpf(1.0f + e) - 1.0f;
}

// x (B, D, K) -> xt[(b*K+k)*D + t] = x[b][t][k]
__global__ __launch_bounds__(256) void transpose_x(const float* __restrict__ x,
                                                   float* __restrict__ xt) {
  __shared__ float tile[32][33];
  int b = blockIdx.x, t0 = blockIdx.y * 32, k0 = blockIdx.z * 32;
  int tx = threadIdx.x, ty = threadIdx.y;
#pragma unroll
  for (int i = 0; i < 32; i += 8) {
    int t = t0 + ty + i, k = k0 + tx;
    tile[ty + i][tx] = (t < DD && k < KK) ? x[((size_t)b * DD + t) * KK + k] : 0.0f;
  }
  __syncthreads();
#pragma unroll
  for (int i = 0; i < 32; i += 8) {
    int k = k0 + ty + i, t = t0 + tx;
    if (k < KK && t < DD) xt[((size_t)b * KK + k) * DD + t] = tile[tx][ty + i];
  }
}

// first zero index (else D), one wave per sequence
__global__ __launch_bounds__(64) void compute_lengths(const float* __restrict__ xt,
                                                      int* __restrict__ lengths) {
  int n = blockIdx.x, lane = threadIdx.x;
  int m = DD;
  for (int t = lane; t < DD; t += 64) {
    if (xt[(size_t)n * DD + t] == 0.0f) { m = t; break; }
  }
#pragma unroll
  for (int off = 1; off < 64; off <<= 1) {
    int o = __shfl_xor(m, off, 64);
    m = (o < m) ? o : m;
  }
  if (lane == 0) lengths[n] = m;
}

// broadcast lane ((lane & 0x18) | J) within each 8-lane group (BitMode swizzle)
#define BCAST8(hi, J) __int_as_float(__builtin_amdgcn_ds_swizzle((hi), ((J) << 5) | 0x18))

// 8 lanes per (sequence, direction); lane li owns hidden unit li (gate rows li, 8+li, 16+li).
template <int IN_DIM, bool WRITE_SEQ, bool WRITE_FEAT>
__global__ __launch_bounds__(256) void gru_scan(
    const float* __restrict__ in, float* __restrict__ out, float* __restrict__ feat,
    const int* __restrict__ lengths,
    const float* __restrict__ Wih, const float* __restrict__ Whh,
    const float* __restrict__ bih, const float* __restrict__ bhh, int nseq) {
  int tid = blockIdx.x * blockDim.x + threadIdx.x;
  int g = tid >> 3, li = tid & 7;
  if (g >= nseq * 2) return;
  int lseq = g >> 1, dir = g & 1;
  int len = lengths[lseq];

  float wih[3][IN_DIM], whh[3][8], bi3[3], bh3[3];
#pragma unroll
  for (int gt = 0; gt < 3; ++gt) {
    int row = dir * 24 + gt * 8 + li;
#pragma unroll
    for (int j = 0; j < IN_DIM; ++j) wih[gt][j] = Wih[row * IN_DIM + j];
#pragma unroll
    for (int j = 0; j < 8; ++j) whh[gt][j] = Whh[row * 8 + j];
    bi3[gt] = bih[row];
    bh3[gt] = bhh[row];
  }

  int steps = (WRITE_FEAT && dir == 1) ? 1 : len;  // last layer bwd: only first step matters
  float h = 0.0f;
  const float* basep = in + (size_t)lseq * DD * IN_DIM;

  float xv[IN_DIM];
  {
    int tt0 = (dir == 0) ? 0 : (len - 1);
    if constexpr (IN_DIM == 1) {
      xv[0] = basep[tt0];
    } else {
      const float4* p = reinterpret_cast<const float4*>(basep + (size_t)tt0 * 16);
#pragma unroll
      for (int q = 0; q < 4; ++q) {
        float4 v = p[q];
        xv[4*q] = v.x; xv[4*q+1] = v.y; xv[4*q+2] = v.z; xv[4*q+3] = v.w;
      }
    }
  }

  for (int t = 0; t < steps; ++t) {
    // broadcast h across the 8-lane group (LDS pipe; overlaps with gi FMAs)
    int hi = __float_as_int(h);
    float hb[8];
    hb[0] = BCAST8(hi, 0);
    hb[1] = BCAST8(hi, 1);
    hb[2] = BCAST8(hi, 2);
    hb[3] = BCAST8(hi, 3);
    hb[4] = BCAST8(hi, 4);
    hb[5] = BCAST8(hi, 5);
    hb[6] = BCAST8(hi, 6);
    hb[7] = BCAST8(hi, 7);

    // gi = Wih @ x_t + bih (current input, fully consumed here)
    float a0 = bi3[0], a1 = bi3[1], a2 = bi3[2];
#pragma unroll
    for (int j = 0; j < IN_DIM; ++j) {
      a0 += wih[0][j] * xv[j];
      a1 += wih[1][j] * xv[j];
      a2 += wih[2][j] * xv[j];
    }

    // prefetch next step's input (xv is dead now; latency hides under gh/activations)
    int tn = (t + 1 < steps) ? (t + 1) : t;
    int ttn = (dir == 0) ? tn : (len - 1 - tn);
    if constexpr (IN_DIM == 1) {
      xv[0] = basep[ttn];
    } else {
      const float4* p = reinterpret_cast<const float4*>(basep + (size_t)ttn * 16);
#pragma unroll
      for (int q = 0; q < 4; ++q) {
        float4 v = p[q];
        xv[4*q] = v.x; xv[4*q+1] = v.y; xv[4*q+2] = v.z; xv[4*q+3] = v.w;
      }
    }

    // gh = Whh @ h + bhh
    float g0 = bh3[0], g1 = bh3[1], g2 = bh3[2];
#pragma unroll
    for (int j = 0; j < 8; ++j) {
      g0 += whh[0][j] * hb[j];
      g1 += whh[1][j] * hb[j];
      g2 += whh[2][j] * hb[j];
    }

    float r = fast_sigmoid(a0 + g0);
    float z = fast_sigmoid(a1 + g1);
    float n = fast_tanh(a2 + r * g2);
    h = z * (h - n) + n;  // == (1-z)*n + z*h

    if (WRITE_SEQ) {
      int tt = (dir == 0) ? t : (len - 1 - t);
      out[((size_t)lseq * DD + tt) * 16 + dir * 8 + li] = h;
    }
  }
  if (WRITE_FEAT) feat[(size_t)lseq * 16 + dir * 8 + li] = h;
}

__global__ __launch_bounds__(256) void head_kernel(
    const float* __restrict__ feat, const float* __restrict__ w1,
    const float* __restrict__ b1, const float* __restrict__ w2,
    const float* __restrict__ b2, float* __restrict__ out) {
  int n = blockIdx.x * blockDim.x + threadIdx.x;
  if (n >= NN) return;
  float f[16];
  const float4* p = reinterpret_cast<const float4*>(feat + (size_t)n * 16);
#pragma unroll
  for (int q = 0; q < 4; ++q) {
    float4 v = p[q];
    f[4*q] = v.x; f[4*q+1] = v.y; f[4*q+2] = v.z; f[4*q+3] = v.w;
  }
  float y[8];
#pragma unroll
  for (int o = 0; o < 8; ++o) {
    float s = b1[o];
#pragma unroll
    for (int j = 0; j < 16; ++j) s += f[j] * w1[o * 16 + j];
    y[o] = (s > 0.0f) ? s : 0.2f * s;  // leaky_relu 0.2
  }
#pragma unroll
  for (int o2 = 0; o2 < 8; ++o2) {
    float s = b2[o2];
#pragma unroll
    for (int o = 0; o < 8; ++o) s += y[o] * w2[o2 * 8 + o];
    out[(size_t)n * 8 + o2] = s;
  }
}

extern "C" void kernel_launch(void* const* d_in, const int* in_sizes, int n_in,
                              void* d_out, int out_size, void* d_ws, size_t ws_size,
                              hipStream_t stream) {
  const float* x      = (const float*)d_in[0];
  const float* w_ih0  = (const float*)d_in[1];
  const float* w_hh0  = (const float*)d_in[2];
  const float* b_ih0  = (const float*)d_in[3];
  const float* b_hh0  = (const float*)d_in[4];
  const float* w_ih   = (const float*)d_in[5];
  const float* w_hh   = (const float*)d_in[6];
  const float* b_ih   = (const float*)d_in[7];
  const float* b_hh   = (const float*)d_in[8];
  const float* lin1_w = (const float*)d_in[9];
  const float* lin1_b = (const float*)d_in[10];
  const float* lin2_w = (const float*)d_in[11];
  const float* lin2_b = (const float*)d_in[12];
  float* out = (float*)d_out;

  char* ws = (char*)d_ws;
  size_t off = 0;
  auto alloc = [&](size_t bytes) -> void* {
    void* p = ws + off;
    off += (bytes + 255) & ~(size_t)255;
    return p;
  };
  float* xt      = (float*)alloc((size_t)NN * DD * sizeof(float));
  int*   lengths = (int*)  alloc((size_t)NN * sizeof(int));
  float* feat    = (float*)alloc((size_t)NN * 16 * sizeof(float));
  size_t base = off;
  size_t per_seq = (size_t)DD * 16 * sizeof(float) * 2;  // two ping-pong buffers
  int Nc = NN;
  if (base + (size_t)NN * per_seq > ws_size) {
    size_t avail = (ws_size > base) ? (ws_size - base) : 0;
    size_t nc = avail / per_seq;
    if (nc < 1) nc = 1;
    if (nc > (size_t)NN) nc = NN;
    Nc = (int)nc;
  }
  float* bufA = (float*)alloc((size_t)Nc * DD * 16 * sizeof(float));
  float* bufB = (float*)alloc((size_t)Nc * DD * 16 * sizeof(float));

  dim3 gT(BB, (DD + 31) / 32, (KK + 31) / 32), bT(32, 8, 1);
  hipLaunchKernelGGL(transpose_x, gT, bT, 0, stream, x, xt);
  hipLaunchKernelGGL(compute_lengths, dim3(NN), dim3(64), 0, stream, xt, lengths);

  for (int s0 = 0; s0 < NN; s0 += Nc) {
    int ns = (NN - s0 < Nc) ? (NN - s0) : Nc;
    int blocks = (ns * 16 + 255) / 256;
    gru_scan<1, true, false><<<blocks, 256, 0, stream>>>(
        xt + (size_t)s0 * DD, bufA, nullptr, lengths + s0,
        w_ih0, w_hh0, b_ih0, b_hh0, ns);
    gru_scan<16, true, false><<<blocks, 256, 0, stream>>>(
        bufA, bufB, nullptr, lengths + s0,
        w_ih + 0 * 2 * 24 * 16, w_hh + 0 * 2 * 24 * 8,
        b_ih + 0 * 2 * 24, b_hh + 0 * 2 * 24, ns);
    gru_scan<16, true, false><<<blocks, 256, 0, stream>>>(
        bufB, bufA, nullptr, lengths + s0,
        w_ih + 1 * 2 * 24 * 16, w_hh + 1 * 2 * 24 * 8,
        b_ih + 1 * 2 * 24, b_hh + 1 * 2 * 24, ns);
    gru_scan<16, false, true><<<blocks, 256, 0, stream>>>(
        bufA, nullptr, feat + (size_t)s0 * 16, lengths + s0,
        w_ih + 2 * 2 * 24 * 16, w_hh + 2 * 2 * 24 * 8,
        b_ih + 2 * 2 * 24, b_hh + 2 * 2 * 24, ns);
  }
  hipLaunchKernelGGL(head_kernel, dim3((NN + 255) / 256), dim3(256), 0, stream,
                     feat, lin1_w, lin1_b, lin2_w, lin2_b, out);
}

// Round 4
// 1209.717 us; speedup vs baseline: 1.2001x; 1.2001x over previous
//
#include <hip/hip_runtime.h>

#define BB 32
#define DD 400
#define KK 200
#define NN (BB*KK)
#define NBINS 512

__device__ __forceinline__ float fast_sigmoid(float x) {
  float e = __builtin_amdgcn_exp2f(-1.4426950408889634f * x);
  return __builtin_amdgcn_rcpf(1.0f + e);
}
__device__ __forceinline__ float fast_tanh(float x) {
  float e = __builtin_amdgcn_exp2f(-2.8853900817779268f * x);
  return 2.0f * __builtin_amdgcn_rcpf(1.0f + e) - 1.0f;
}

// quad_perm broadcast P within each aligned 4-lane quad (VALU pipe, no LDS)
#define QPERM(v, P) __int_as_float(__builtin_amdgcn_mov_dpp(__float_as_int(v), (P)*0x55, 0xF, 0xF, true))
// lane ^ 4 exchange (BitMode swizzle: xor=4, and=0x1F)
#define SWZ_XOR4(v) __int_as_float(__builtin_amdgcn_ds_swizzle(__float_as_int(v), 0x101F))

// NOTE: parameter names must not collide with .x/.y/.z/.w member tokens
#define DOT4(ACC_, W_, V_) \
  ACC_ = fmaf((W_).x, (V_).x, fmaf((W_).y, (V_).y, fmaf((W_).z, (V_).z, fmaf((W_).w, (V_).w, (ACC_)))))

// x (B, D, K) -> xt[(b*K+k)*D + t] = x[b][t][k]
__global__ __launch_bounds__(256) void transpose_x(const float* __restrict__ x,
                                                   float* __restrict__ xt) {
  __shared__ float tile[32][33];
  int b = blockIdx.x, t0 = blockIdx.y * 32, k0 = blockIdx.z * 32;
  int tx = threadIdx.x, ty = threadIdx.y;
#pragma unroll
  for (int i = 0; i < 32; i += 8) {
    int t = t0 + ty + i, k = k0 + tx;
    tile[ty + i][tx] = (t < DD && k < KK) ? x[((size_t)b * DD + t) * KK + k] : 0.0f;
  }
  __syncthreads();
#pragma unroll
  for (int i = 0; i < 32; i += 8) {
    int k = k0 + ty + i, t = t0 + tx;
    if (k < KK && t < DD) xt[((size_t)b * KK + k) * DD + t] = tile[tx][ty + i];
  }
}

// first zero index (else D) per sequence + length histogram
__global__ __launch_bounds__(64) void compute_lengths(const float* __restrict__ xt,
                                                      int* __restrict__ lengths,
                                                      int* __restrict__ hist) {
  int n = blockIdx.x, lane = threadIdx.x;
  int m = DD;
  for (int t = lane; t < DD; t += 64) {
    if (xt[(size_t)n * DD + t] == 0.0f) { m = t; break; }
  }
#pragma unroll
  for (int off = 1; off < 64; off <<= 1) {
    int o = __shfl_xor(m, off, 64);
    m = (o < m) ? o : m;
  }
  if (lane == 0) {
    lengths[n] = m;
    atomicAdd(&hist[m], 1);
  }
}

__global__ void scan_offsets(const int* __restrict__ hist, int* __restrict__ offs) {
  if (threadIdx.x == 0 && blockIdx.x == 0) {
    int acc = 0;
    for (int i = 0; i < NBINS; ++i) { offs[i] = acc; acc += hist[i]; }
  }
}

__global__ __launch_bounds__(256) void scatter_sort(const int* __restrict__ lengths,
                                                    int* __restrict__ offs,
                                                    int* __restrict__ order,
                                                    int* __restrict__ len_sorted) {
  int n = blockIdx.x * 256 + threadIdx.x;
  if (n >= NN) return;
  int len = lengths[n];
  int pos = atomicAdd(&offs[len], 1);
  order[pos] = n;
  len_sorted[pos] = len;
}

// 8 lanes per (sorted-seq, dir); lane li owns hidden unit li.
// h-exchange: 1 ds_swizzle (lane^4) + 8 quad_perm DPP movs; Whh pre-permuted per lane.
template <int IN_DIM, bool IND_IN, bool WRITE_SEQ, bool FWD_ONLY>
__global__ __launch_bounds__(256) void gru_scan(
    const float* __restrict__ in, float* __restrict__ out, float* __restrict__ feat,
    const int* __restrict__ len_sorted, const int* __restrict__ order,
    const float* __restrict__ Wih, const float* __restrict__ Whh,
    const float* __restrict__ bih, const float* __restrict__ bhh, int nseq) {
  int tid = blockIdx.x * blockDim.x + threadIdx.x;
  int g = tid >> 3, li = tid & 7;
  int ngroups = FWD_ONLY ? nseq : nseq * 2;
  if (g >= ngroups) return;
  int sg  = FWD_ONLY ? g : (g >> 1);
  int dir = FWD_ONLY ? 0 : (g & 1);
  int len = len_sorted[sg];

  int qb = li & 4, qbx = qb ^ 4;
  float wA[3][4], wB[3][4], bi3[3], bh3[3];
  float4 wi4[3][4];
  float wi1[3];
#pragma unroll
  for (int gt = 0; gt < 3; ++gt) {
    int row = dir * 24 + gt * 8 + li;
    if constexpr (IN_DIM == 16) {
      const float4* wp = reinterpret_cast<const float4*>(Wih + row * 16);
#pragma unroll
      for (int q = 0; q < 4; ++q) wi4[gt][q] = wp[q];
    } else {
      wi1[gt] = Wih[row];
    }
#pragma unroll
    for (int p = 0; p < 4; ++p) {
      wA[gt][p] = Whh[row * 8 + qb + p];
      wB[gt][p] = Whh[row * 8 + qbx + p];
    }
    bi3[gt] = bih[row];
    bh3[gt] = bhh[row];
  }

  int steps = len;
  float h = 0.0f;
  const float* basep = IND_IN ? (in + (size_t)order[sg] * DD)
                              : (in + (size_t)sg * DD * IN_DIM);
  const float* px = basep + (size_t)((dir == 0) ? 0 : (len - 1)) * IN_DIM;
  ptrdiff_t xstep = (dir == 0) ? IN_DIM : -IN_DIM;

  float* pw = nullptr; ptrdiff_t wstep = 0;
  if constexpr (WRITE_SEQ) {
    pw = out + ((size_t)sg * DD + ((dir == 0) ? 0 : (len - 1))) * 16 + dir * 8 + li;
    wstep = (dir == 0) ? 16 : -16;
  }

  float4 x0, x1, x2, x3; float xs;
  auto loadx = [&]() {
    if constexpr (IN_DIM == 1) {
      xs = *px;
    } else {
      const float4* q = reinterpret_cast<const float4*>(px);
      x0 = q[0]; x1 = q[1]; x2 = q[2]; x3 = q[3];
    }
    px += xstep;
  };
  loadx();

  auto step = [&](bool pf) {
    // gi = Wih @ x_t + bih (consumes current x regs)
    float a0 = bi3[0], a1 = bi3[1], a2 = bi3[2];
    if constexpr (IN_DIM == 1) {
      a0 = fmaf(wi1[0], xs, a0);
      a1 = fmaf(wi1[1], xs, a1);
      a2 = fmaf(wi1[2], xs, a2);
    } else {
      DOT4(a0, wi4[0][0], x0); DOT4(a0, wi4[0][1], x1); DOT4(a0, wi4[0][2], x2); DOT4(a0, wi4[0][3], x3);
      DOT4(a1, wi4[1][0], x0); DOT4(a1, wi4[1][1], x1); DOT4(a1, wi4[1][2], x2); DOT4(a1, wi4[1][3], x3);
      DOT4(a2, wi4[2][0], x0); DOT4(a2, wi4[2][1], x1); DOT4(a2, wi4[2][2], x2); DOT4(a2, wi4[2][3], x3);
    }
    if (pf) loadx();  // prefetch next step's input (hides under gh+activations)

    // h all-gather within 8-lane group
    float hx = SWZ_XOR4(h);
    float hq0 = QPERM(h, 0), hq1 = QPERM(h, 1), hq2 = QPERM(h, 2), hq3 = QPERM(h, 3);
    float hx0 = QPERM(hx, 0), hx1 = QPERM(hx, 1), hx2 = QPERM(hx, 2), hx3 = QPERM(hx, 3);

    float g0 = bh3[0], g1 = bh3[1], g2 = bh3[2];
    g0 = fmaf(wA[0][0], hq0, fmaf(wA[0][1], hq1, fmaf(wA[0][2], hq2, fmaf(wA[0][3], hq3, g0))));
    g0 = fmaf(wB[0][0], hx0, fmaf(wB[0][1], hx1, fmaf(wB[0][2], hx2, fmaf(wB[0][3], hx3, g0))));
    g1 = fmaf(wA[1][0], hq0, fmaf(wA[1][1], hq1, fmaf(wA[1][2], hq2, fmaf(wA[1][3], hq3, g1))));
    g1 = fmaf(wB[1][0], hx0, fmaf(wB[1][1], hx1, fmaf(wB[1][2], hx2, fmaf(wB[1][3], hx3, g1))));
    g2 = fmaf(wA[2][0], hq0, fmaf(wA[2][1], hq1, fmaf(wA[2][2], hq2, fmaf(wA[2][3], hq3, g2))));
    g2 = fmaf(wB[2][0], hx0, fmaf(wB[2][1], hx1, fmaf(wB[2][2], hx2, fmaf(wB[2][3], hx3, g2))));

    float r = fast_sigmoid(a0 + g0);
    float z = fast_sigmoid(a1 + g1);
    float n = fast_tanh(a2 + r * g2);
    h = z * (h - n) + n;  // == (1-z)*n + z*h

    if constexpr (WRITE_SEQ) { *pw = h; pw += wstep; }
  };

  for (int t = 0; t < steps - 1; ++t) step(true);
  step(false);  // peeled last iteration: no prefetch, no bounds mask in hot loop

  if constexpr (!WRITE_SEQ) {
    feat[(size_t)order[sg] * 16 + dir * 8 + li] = h;
  }
}

// last layer, bwd direction: only t = len-1 matters and h0 = 0 => gh = bhh (closed form)
__global__ __launch_bounds__(256) void bwd_last(
    const float* __restrict__ in, float* __restrict__ feat,
    const int* __restrict__ len_sorted, const int* __restrict__ order,
    const float* __restrict__ Wih, const float* __restrict__ bih,
    const float* __restrict__ bhh, int nseq) {
  int tid = blockIdx.x * blockDim.x + threadIdx.x;
  int sg = tid >> 3, li = tid & 7;
  if (sg >= nseq) return;
  int len = len_sorted[sg];
  const float4* xp = reinterpret_cast<const float4*>(in + ((size_t)sg * DD + (len - 1)) * 16);
  float4 x0 = xp[0], x1 = xp[1], x2 = xp[2], x3 = xp[3];
  float a[3], bh[3];
#pragma unroll
  for (int gt = 0; gt < 3; ++gt) {
    int row = 24 + gt * 8 + li;  // dir=1 rows
    const float4* wp = reinterpret_cast<const float4*>(Wih + row * 16);
    float acc = bih[row];
    DOT4(acc, wp[0], x0); DOT4(acc, wp[1], x1); DOT4(acc, wp[2], x2); DOT4(acc, wp[3], x3);
    a[gt] = acc;
    bh[gt] = bhh[row];
  }
  float r = fast_sigmoid(a[0] + bh[0]);
  float z = fast_sigmoid(a[1] + bh[1]);
  float n = fast_tanh(a[2] + r * bh[2]);
  float h = (1.0f - z) * n;
  feat[(size_t)order[sg] * 16 + 8 + li] = h;
}

__global__ __launch_bounds__(256) void head_kernel(
    const float* __restrict__ feat, const float* __restrict__ w1,
    const float* __restrict__ b1, const float* __restrict__ w2,
    const float* __restrict__ b2, float* __restrict__ out) {
  int n = blockIdx.x * blockDim.x + threadIdx.x;
  if (n >= NN) return;
  float f[16];
  const float4* p = reinterpret_cast<const float4*>(feat + (size_t)n * 16);
#pragma unroll
  for (int q = 0; q < 4; ++q) {
    float4 v = p[q];
    f[4*q] = v.x; f[4*q+1] = v.y; f[4*q+2] = v.z; f[4*q+3] = v.w;
  }
  float y[8];
#pragma unroll
  for (int o = 0; o < 8; ++o) {
    float s = b1[o];
#pragma unroll
    for (int j = 0; j < 16; ++j) s += f[j] * w1[o * 16 + j];
    y[o] = (s > 0.0f) ? s : 0.2f * s;
  }
#pragma unroll
  for (int o2 = 0; o2 < 8; ++o2) {
    float s = b2[o2];
#pragma unroll
    for (int o = 0; o < 8; ++o) s += y[o] * w2[o2 * 8 + o];
    out[(size_t)n * 8 + o2] = s;
  }
}

extern "C" void kernel_launch(void* const* d_in, const int* in_sizes, int n_in,
                              void* d_out, int out_size, void* d_ws, size_t ws_size,
                              hipStream_t stream) {
  const float* x      = (const float*)d_in[0];
  const float* w_ih0  = (const float*)d_in[1];
  const float* w_hh0  = (const float*)d_in[2];
  const float* b_ih0  = (const float*)d_in[3];
  const float* b_hh0  = (const float*)d_in[4];
  const float* w_ih   = (const float*)d_in[5];
  const float* w_hh   = (const float*)d_in[6];
  const float* b_ih   = (const float*)d_in[7];
  const float* b_hh   = (const float*)d_in[8];
  const float* lin1_w = (const float*)d_in[9];
  const float* lin1_b = (const float*)d_in[10];
  const float* lin2_w = (const float*)d_in[11];
  const float* lin2_b = (const float*)d_in[12];
  float* out = (float*)d_out;

  char* ws = (char*)d_ws;
  size_t off = 0;
  auto alloc = [&](size_t bytes) -> void* {
    void* p = ws + off;
    off += (bytes + 255) & ~(size_t)255;
    return p;
  };
  float* xt         = (float*)alloc((size_t)NN * DD * sizeof(float));
  int*   lengths    = (int*)  alloc((size_t)NN * sizeof(int));
  int*   hist       = (int*)  alloc(NBINS * sizeof(int));
  int*   offs       = (int*)  alloc(NBINS * sizeof(int));
  int*   order      = (int*)  alloc((size_t)NN * sizeof(int));
  int*   len_sorted = (int*)  alloc((size_t)NN * sizeof(int));
  float* feat       = (float*)alloc((size_t)NN * 16 * sizeof(float));
  size_t base = off;
  size_t per_seq = (size_t)DD * 16 * sizeof(float) * 2 + 512;
  int Nc = NN;
  if (base + (size_t)NN * per_seq > ws_size) {
    size_t avail = (ws_size > base) ? (ws_size - base) : 0;
    size_t nc = avail / per_seq;
    if (nc < 1) nc = 1;
    if (nc > (size_t)NN) nc = NN;
    Nc = (int)nc;
  }
  float* bufA = (float*)alloc((size_t)Nc * DD * 16 * sizeof(float) + 256);
  float* bufB = (float*)alloc((size_t)Nc * DD * 16 * sizeof(float) + 256);

  hipMemsetAsync(hist, 0, NBINS * sizeof(int), stream);
  dim3 gT(BB, (DD + 31) / 32, (KK + 31) / 32), bT(32, 8, 1);
  hipLaunchKernelGGL(transpose_x, gT, bT, 0, stream, x, xt);
  hipLaunchKernelGGL(compute_lengths, dim3(NN), dim3(64), 0, stream, xt, lengths, hist);
  hipLaunchKernelGGL(scan_offsets, dim3(1), dim3(64), 0, stream, hist, offs);
  hipLaunchKernelGGL(scatter_sort, dim3((NN + 255) / 256), dim3(256), 0, stream,
                     lengths, offs, order, len_sorted);

  for (int s0 = 0; s0 < NN; s0 += Nc) {
    int ns = (NN - s0 < Nc) ? (NN - s0) : Nc;
    int blk2 = (ns * 16 + 255) / 256;  // both dirs
    int blk1 = (ns * 8 + 255) / 256;   // fwd only / bwd_last
    gru_scan<1, true, true, false><<<blk2, 256, 0, stream>>>(
        xt, bufA, nullptr, len_sorted + s0, order + s0,
        w_ih0, w_hh0, b_ih0, b_hh0, ns);
    gru_scan<16, false, true, false><<<blk2, 256, 0, stream>>>(
        bufA, bufB, nullptr, len_sorted + s0, order + s0,
        w_ih + 0 * 2 * 24 * 16, w_hh + 0 * 2 * 24 * 8,
        b_ih + 0 * 2 * 24, b_hh + 0 * 2 * 24, ns);
    gru_scan<16, false, true, false><<<blk2, 256, 0, stream>>>(
        bufB, bufA, nullptr, len_sorted + s0, order + s0,
        w_ih + 1 * 2 * 24 * 16, w_hh + 1 * 2 * 24 * 8,
        b_ih + 1 * 2 * 24, b_hh + 1 * 2 * 24, ns);
    gru_scan<16, false, false, true><<<blk1, 256, 0, stream>>>(
        bufA, nullptr, feat, len_sorted + s0, order + s0,
        w_ih + 2 * 2 * 24 * 16, w_hh + 2 * 2 * 24 * 8,
        b_ih + 2 * 2 * 24, b_hh + 2 * 2 * 24, ns);
    hipLaunchKernelGGL(bwd_last, dim3(blk1), dim3(256), 0, stream,
                       bufA, feat, len_sorted + s0, order + s0,
                       w_ih + 2 * 2 * 24 * 16, b_ih + 2 * 2 * 24, b_hh + 2 * 2 * 24, ns);
  }
  hipLaunchKernelGGL(head_kernel, dim3((NN + 255) / 256), dim3(256), 0, stream,
                     feat, lin1_w, lin1_b, lin2_w, lin2_b, out);
}

// Round 5
// 947.060 us; speedup vs baseline: 1.5329x; 1.2773x over previous
//
#include <hip/hip_runtime.h>

#define BB 32
#define DD 400
#define KK 200
#define NN (BB*KK)
#define NBINS 512

__device__ __forceinline__ float fast_sigmoid(float x) {
  float e = __builtin_amdgcn_exp2f(-1.4426950408889634f * x);
  return __builtin_amdgcn_rcpf(1.0f + e);
}
__device__ __forceinline__ float fast_tanh(float x) {
  float e = __builtin_amdgcn_exp2f(-2.8853900817779268f * x);
  return 2.0f * __builtin_amdgcn_rcpf(1.0f + e) - 1.0f;
}

// quad_perm broadcast P within each aligned 4-lane quad (VALU pipe, no LDS)
#define QPERM(v, P) __int_as_float(__builtin_amdgcn_mov_dpp(__float_as_int(v), (P)*0x55, 0xF, 0xF, true))
// lane ^ 4 exchange (BitMode swizzle: xor=4, and=0x1F)
#define SWZ_XOR4(v) __int_as_float(__builtin_amdgcn_ds_swizzle(__float_as_int(v), 0x101F))

// NOTE: parameter names must not collide with .x/.y/.z/.w member tokens
#define DOT4(ACC_, W_, V_) \
  ACC_ = fmaf((W_).x, (V_).x, fmaf((W_).y, (V_).y, fmaf((W_).z, (V_).z, fmaf((W_).w, (V_).w, (ACC_)))))

// x (B, D, K) -> xt[(b*K+k)*D + t] = x[b][t][k]
__global__ __launch_bounds__(256) void transpose_x(const float* __restrict__ x,
                                                   float* __restrict__ xt) {
  __shared__ float tile[32][33];
  int b = blockIdx.x, t0 = blockIdx.y * 32, k0 = blockIdx.z * 32;
  int tx = threadIdx.x, ty = threadIdx.y;
#pragma unroll
  for (int i = 0; i < 32; i += 8) {
    int t = t0 + ty + i, k = k0 + tx;
    tile[ty + i][tx] = (t < DD && k < KK) ? x[((size_t)b * DD + t) * KK + k] : 0.0f;
  }
  __syncthreads();
#pragma unroll
  for (int i = 0; i < 32; i += 8) {
    int k = k0 + ty + i, t = t0 + tx;
    if (k < KK && t < DD) xt[((size_t)b * KK + k) * DD + t] = tile[tx][ty + i];
  }
}

// first zero index (else D) per sequence + length histogram
__global__ __launch_bounds__(64) void compute_lengths(const float* __restrict__ xt,
                                                      int* __restrict__ lengths,
                                                      int* __restrict__ hist) {
  int n = blockIdx.x, lane = threadIdx.x;
  int m = DD;
  for (int t = lane; t < DD; t += 64) {
    if (xt[(size_t)n * DD + t] == 0.0f) { m = t; break; }
  }
#pragma unroll
  for (int off = 1; off < 64; off <<= 1) {
    int o = __shfl_xor(m, off, 64);
    m = (o < m) ? o : m;
  }
  if (lane == 0) {
    lengths[n] = m;
    atomicAdd(&hist[m], 1);
  }
}

__global__ void scan_offsets(const int* __restrict__ hist, int* __restrict__ offs) {
  if (threadIdx.x == 0 && blockIdx.x == 0) {
    int acc = 0;
    for (int i = 0; i < NBINS; ++i) { offs[i] = acc; acc += hist[i]; }
  }
}

__global__ __launch_bounds__(256) void scatter_sort(const int* __restrict__ lengths,
                                                    int* __restrict__ offs,
                                                    int* __restrict__ order,
                                                    int* __restrict__ len_sorted) {
  int n = blockIdx.x * 256 + threadIdx.x;
  if (n >= NN) return;
  int len = lengths[n];
  int pos = atomicAdd(&offs[len], 1);
  order[pos] = n;
  len_sorted[pos] = len;
}

// 8 lanes per (sorted-seq, dir); lane li owns hidden unit li.
// h-exchange: 1 ds_swizzle (issued at end of prev step, latency hidden) + 8 quad_perm DPP.
// x stream: 4-step-deep register prefetch pipeline (covers ~900cy HBM latency).
template <int IN_DIM, bool IND_IN, bool WRITE_SEQ, bool FWD_ONLY>
__global__ __launch_bounds__(256) void gru_scan(
    const float* __restrict__ in, float* __restrict__ out, float* __restrict__ feat,
    const int* __restrict__ len_sorted, const int* __restrict__ order,
    const float* __restrict__ Wih, const float* __restrict__ Whh,
    const float* __restrict__ bih, const float* __restrict__ bhh, int nseq) {
  int tid = blockIdx.x * blockDim.x + threadIdx.x;
  int g = tid >> 3, li = tid & 7;
  int ngroups = FWD_ONLY ? nseq : nseq * 2;
  if (g >= ngroups) return;
  int sg  = FWD_ONLY ? g : (g >> 1);
  int dir = FWD_ONLY ? 0 : (g & 1);
  int len = len_sorted[sg];

  int qb = li & 4, qbx = qb ^ 4;
  float wA[3][4], wB[3][4], bi3[3], bh3[3];
  float4 wi4[3][4];
  float wi1[3];
#pragma unroll
  for (int gt = 0; gt < 3; ++gt) {
    int row = dir * 24 + gt * 8 + li;
    if constexpr (IN_DIM == 16) {
      const float4* wp = reinterpret_cast<const float4*>(Wih + row * 16);
#pragma unroll
      for (int q = 0; q < 4; ++q) wi4[gt][q] = wp[q];
    } else {
      wi1[gt] = Wih[row];
    }
#pragma unroll
    for (int p = 0; p < 4; ++p) {
      wA[gt][p] = Whh[row * 8 + qb + p];
      wB[gt][p] = Whh[row * 8 + qbx + p];
    }
    bi3[gt] = bih[row];
    bh3[gt] = bhh[row];
  }

  int steps = len;  // >= 200 always
  float h = 0.0f, hx = 0.0f;  // hx = swizzled h from end of previous step
  const float* basep = IND_IN ? (in + (size_t)order[sg] * DD)
                              : (in + (size_t)sg * DD * IN_DIM);
  const float* px = basep + (size_t)((dir == 0) ? 0 : (len - 1)) * IN_DIM;
  ptrdiff_t xstep = (dir == 0) ? IN_DIM : -IN_DIM;

  float* pw = nullptr; ptrdiff_t wstep = 0;
  if constexpr (WRITE_SEQ) {
    pw = out + ((size_t)sg * DD + ((dir == 0) ? 0 : (len - 1))) * 16 + dir * 8 + li;
    wstep = (dir == 0) ? 16 : -16;
  }

  // shared epilogue of a step: gh, activations, h update, next-step swizzle, store
  auto core = [&](float a0, float a1, float a2) {
    float hq0 = QPERM(h, 0), hq1 = QPERM(h, 1), hq2 = QPERM(h, 2), hq3 = QPERM(h, 3);
    float hx0 = QPERM(hx, 0), hx1 = QPERM(hx, 1), hx2 = QPERM(hx, 2), hx3 = QPERM(hx, 3);

    float gA0 = fmaf(wA[0][0], hq0, fmaf(wA[0][1], hq1, fmaf(wA[0][2], hq2, fmaf(wA[0][3], hq3, bh3[0]))));
    float gB0 = fmaf(wB[0][0], hx0, fmaf(wB[0][1], hx1, fmaf(wB[0][2], hx2, wB[0][3] * hx3)));
    float gA1 = fmaf(wA[1][0], hq0, fmaf(wA[1][1], hq1, fmaf(wA[1][2], hq2, fmaf(wA[1][3], hq3, bh3[1]))));
    float gB1 = fmaf(wB[1][0], hx0, fmaf(wB[1][1], hx1, fmaf(wB[1][2], hx2, wB[1][3] * hx3)));
    float gA2 = fmaf(wA[2][0], hq0, fmaf(wA[2][1], hq1, fmaf(wA[2][2], hq2, fmaf(wA[2][3], hq3, bh3[2]))));
    float gB2 = fmaf(wB[2][0], hx0, fmaf(wB[2][1], hx1, fmaf(wB[2][2], hx2, wB[2][3] * hx3)));

    float r = fast_sigmoid(a0 + gA0 + gB0);
    float z = fast_sigmoid(a1 + gA1 + gB1);
    float n = fast_tanh(a2 + r * (gA2 + gB2));
    h = z * (h - n) + n;  // == (1-z)*n + z*h
    hx = SWZ_XOR4(h);     // issue now; consumed next step after gi FMAs (latency hidden)
    if constexpr (WRITE_SEQ) { *pw = h; pw += wstep; }
  };

  if constexpr (IN_DIM == 1) {
    float s0_, s1_, s2_, s3_;
    auto ld = [&](float& S_) { S_ = *px; px += xstep; };
    auto st = [&](float& S_, bool pf) {
      float a0 = fmaf(wi1[0], S_, bi3[0]);
      float a1 = fmaf(wi1[1], S_, bi3[1]);
      float a2 = fmaf(wi1[2], S_, bi3[2]);
      if (pf) ld(S_);  // prefetch step t+4
      core(a0, a1, a2);
    };
    ld(s0_); ld(s1_); ld(s2_); ld(s3_);
    int t = 0;
    for (; t + 4 <= steps; t += 4) {
      st(s0_, true); st(s1_, true); st(s2_, true); st(s3_, true);
    }
    int rem = steps - t;
    if (rem > 0) st(s0_, false);
    if (rem > 1) st(s1_, false);
    if (rem > 2) st(s2_, false);
  } else {
    float4 b0_[4], b1_[4], b2_[4], b3_[4];
    auto ld = [&](float4 (&B_)[4]) {
      const float4* q4 = reinterpret_cast<const float4*>(px);
      B_[0] = q4[0]; B_[1] = q4[1]; B_[2] = q4[2]; B_[3] = q4[3];
      px += xstep;
    };
    auto st = [&](float4 (&B_)[4], bool pf) {
      float a0 = bi3[0], a1 = bi3[1], a2 = bi3[2];
      DOT4(a0, wi4[0][0], B_[0]); DOT4(a0, wi4[0][1], B_[1]); DOT4(a0, wi4[0][2], B_[2]); DOT4(a0, wi4[0][3], B_[3]);
      DOT4(a1, wi4[1][0], B_[0]); DOT4(a1, wi4[1][1], B_[1]); DOT4(a1, wi4[1][2], B_[2]); DOT4(a1, wi4[1][3], B_[3]);
      DOT4(a2, wi4[2][0], B_[0]); DOT4(a2, wi4[2][1], B_[1]); DOT4(a2, wi4[2][2], B_[2]); DOT4(a2, wi4[2][3], B_[3]);
      if (pf) ld(B_);  // prefetch step t+4
      core(a0, a1, a2);
    };
    ld(b0_); ld(b1_); ld(b2_); ld(b3_);
    int t = 0;
    for (; t + 4 <= steps; t += 4) {
      st(b0_, true); st(b1_, true); st(b2_, true); st(b3_, true);
    }
    int rem = steps - t;
    if (rem > 0) st(b0_, false);
    if (rem > 1) st(b1_, false);
    if (rem > 2) st(b2_, false);
  }

  if constexpr (!WRITE_SEQ) {
    feat[(size_t)order[sg] * 16 + dir * 8 + li] = h;
  }
}

// last layer, bwd direction: only t = len-1 matters and h0 = 0 => gh = bhh (closed form)
__global__ __launch_bounds__(256) void bwd_last(
    const float* __restrict__ in, float* __restrict__ feat,
    const int* __restrict__ len_sorted, const int* __restrict__ order,
    const float* __restrict__ Wih, const float* __restrict__ bih,
    const float* __restrict__ bhh, int nseq) {
  int tid = blockIdx.x * blockDim.x + threadIdx.x;
  int sg = tid >> 3, li = tid & 7;
  if (sg >= nseq) return;
  int len = len_sorted[sg];
  const float4* xp = reinterpret_cast<const float4*>(in + ((size_t)sg * DD + (len - 1)) * 16);
  float4 x0 = xp[0], x1 = xp[1], x2 = xp[2], x3 = xp[3];
  float a[3], bh[3];
#pragma unroll
  for (int gt = 0; gt < 3; ++gt) {
    int row = 24 + gt * 8 + li;  // dir=1 rows
    const float4* wp = reinterpret_cast<const float4*>(Wih + row * 16);
    float acc = bih[row];
    DOT4(acc, wp[0], x0); DOT4(acc, wp[1], x1); DOT4(acc, wp[2], x2); DOT4(acc, wp[3], x3);
    a[gt] = acc;
    bh[gt] = bhh[row];
  }
  float r = fast_sigmoid(a[0] + bh[0]);
  float z = fast_sigmoid(a[1] + bh[1]);
  float n = fast_tanh(a[2] + r * bh[2]);
  float h = (1.0f - z) * n;
  feat[(size_t)order[sg] * 16 + 8 + li] = h;
}

__global__ __launch_bounds__(256) void head_kernel(
    const float* __restrict__ feat, const float* __restrict__ w1,
    const float* __restrict__ b1, const float* __restrict__ w2,
    const float* __restrict__ b2, float* __restrict__ out) {
  int n = blockIdx.x * blockDim.x + threadIdx.x;
  if (n >= NN) return;
  float f[16];
  const float4* p = reinterpret_cast<const float4*>(feat + (size_t)n * 16);
#pragma unroll
  for (int q = 0; q < 4; ++q) {
    float4 v = p[q];
    f[4*q] = v.x; f[4*q+1] = v.y; f[4*q+2] = v.z; f[4*q+3] = v.w;
  }
  float y[8];
#pragma unroll
  for (int o = 0; o < 8; ++o) {
    float s = b1[o];
#pragma unroll
    for (int j = 0; j < 16; ++j) s += f[j] * w1[o * 16 + j];
    y[o] = (s > 0.0f) ? s : 0.2f * s;
  }
#pragma unroll
  for (int o2 = 0; o2 < 8; ++o2) {
    float s = b2[o2];
#pragma unroll
    for (int o = 0; o < 8; ++o) s += y[o] * w2[o2 * 8 + o];
    out[(size_t)n * 8 + o2] = s;
  }
}

extern "C" void kernel_launch(void* const* d_in, const int* in_sizes, int n_in,
                              void* d_out, int out_size, void* d_ws, size_t ws_size,
                              hipStream_t stream) {
  const float* x      = (const float*)d_in[0];
  const float* w_ih0  = (const float*)d_in[1];
  const float* w_hh0  = (const float*)d_in[2];
  const float* b_ih0  = (const float*)d_in[3];
  const float* b_hh0  = (const float*)d_in[4];
  const float* w_ih   = (const float*)d_in[5];
  const float* w_hh   = (const float*)d_in[6];
  const float* b_ih   = (const float*)d_in[7];
  const float* b_hh   = (const float*)d_in[8];
  const float* lin1_w = (const float*)d_in[9];
  const float* lin1_b = (const float*)d_in[10];
  const float* lin2_w = (const float*)d_in[11];
  const float* lin2_b = (const float*)d_in[12];
  float* out = (float*)d_out;

  char* ws = (char*)d_ws;
  size_t off = 0;
  auto alloc = [&](size_t bytes) -> void* {
    void* p = ws + off;
    off += (bytes + 255) & ~(size_t)255;
    return p;
  };
  alloc(1024);  // front guard (backward prefetch overrun)
  float* xt         = (float*)alloc((size_t)NN * DD * sizeof(float) + 1024);
  int*   lengths    = (int*)  alloc((size_t)NN * sizeof(int));
  int*   hist       = (int*)  alloc(NBINS * sizeof(int));
  int*   offs       = (int*)  alloc(NBINS * sizeof(int));
  int*   order      = (int*)  alloc((size_t)NN * sizeof(int));
  int*   len_sorted = (int*)  alloc((size_t)NN * sizeof(int));
  float* feat       = (float*)alloc((size_t)NN * 16 * sizeof(float));
  size_t base = off;
  size_t per_seq = (size_t)DD * 16 * sizeof(float) * 2 + 1024;
  int Nc = NN;
  if (base + (size_t)NN * per_seq + 8192 > ws_size) {
    size_t avail = (ws_size > base + 8192) ? (ws_size - base - 8192) : 0;
    size_t nc = avail / per_seq;
    if (nc < 1) nc = 1;
    if (nc > (size_t)NN) nc = NN;
    Nc = (int)nc;
  }
  alloc(1024);  // guard before bufA
  float* bufA = (float*)alloc((size_t)Nc * DD * 16 * sizeof(float) + 1024);
  float* bufB = (float*)alloc((size_t)Nc * DD * 16 * sizeof(float) + 1024);

  hipMemsetAsync(hist, 0, NBINS * sizeof(int), stream);
  dim3 gT(BB, (DD + 31) / 32, (KK + 31) / 32), bT(32, 8, 1);
  hipLaunchKernelGGL(transpose_x, gT, bT, 0, stream, x, xt);
  hipLaunchKernelGGL(compute_lengths, dim3(NN), dim3(64), 0, stream, xt, lengths, hist);
  hipLaunchKernelGGL(scan_offsets, dim3(1), dim3(64), 0, stream, hist, offs);
  hipLaunchKernelGGL(scatter_sort, dim3((NN + 255) / 256), dim3(256), 0, stream,
                     lengths, offs, order, len_sorted);

  for (int s0 = 0; s0 < NN; s0 += Nc) {
    int ns = (NN - s0 < Nc) ? (NN - s0) : Nc;
    int blk2 = (ns * 16 + 255) / 256;  // both dirs
    int blk1 = (ns * 8 + 255) / 256;   // fwd only / bwd_last
    gru_scan<1, true, true, false><<<blk2, 256, 0, stream>>>(
        xt, bufA, nullptr, len_sorted + s0, order + s0,
        w_ih0, w_hh0, b_ih0, b_hh0, ns);
    gru_scan<16, false, true, false><<<blk2, 256, 0, stream>>>(
        bufA, bufB, nullptr, len_sorted + s0, order + s0,
        w_ih + 0 * 2 * 24 * 16, w_hh + 0 * 2 * 24 * 8,
        b_ih + 0 * 2 * 24, b_hh + 0 * 2 * 24, ns);
    gru_scan<16, false, true, false><<<blk2, 256, 0, stream>>>(
        bufB, bufA, nullptr, len_sorted + s0, order + s0,
        w_ih + 1 * 2 * 24 * 16, w_hh + 1 * 2 * 24 * 8,
        b_ih + 1 * 2 * 24, b_hh + 1 * 2 * 24, ns);
    gru_scan<16, false, false, true><<<blk1, 256, 0, stream>>>(
        bufA, nullptr, feat, len_sorted + s0, order + s0,
        w_ih + 2 * 2 * 24 * 16, w_hh + 2 * 2 * 24 * 8,
        b_ih + 2 * 2 * 24, b_hh + 2 * 2 * 24, ns);
    hipLaunchKernelGGL(bwd_last, dim3(blk1), dim3(256), 0, stream,
                       bufA, feat, len_sorted + s0, order + s0,
                       w_ih + 2 * 2 * 24 * 16, b_ih + 2 * 2 * 24, b_hh + 2 * 2 * 24, ns);
  }
  hipLaunchKernelGGL(head_kernel, dim3((NN + 255) / 256), dim3(256), 0, stream,
                     feat, lin1_w, lin1_b, lin2_w, lin2_b, out);
}

// Round 6
// 835.278 us; speedup vs baseline: 1.7380x; 1.1338x over previous
//
#include <hip/hip_runtime.h>

#define BB 32
#define DD 400
#define KK 200
#define NN (BB*KK)
#define NBINS 512

typedef float f2 __attribute__((ext_vector_type(2)));

__device__ __forceinline__ float fast_sigmoid(float x) {
  float e = __builtin_amdgcn_exp2f(-1.4426950408889634f * x);
  return __builtin_amdgcn_rcpf(1.0f + e);
}
__device__ __forceinline__ float fast_tanh(float x) {
  float e = __builtin_amdgcn_exp2f(-2.8853900817779268f * x);
  return 2.0f * __builtin_amdgcn_rcpf(1.0f + e) - 1.0f;
}

// quad_perm broadcast P within each aligned 4-lane quad (VALU pipe, no LDS)
#define QPERM(v, P) __int_as_float(__builtin_amdgcn_mov_dpp(__float_as_int(v), (P)*0x55, 0xF, 0xF, true))
// lane ^ 4 exchange (BitMode swizzle: xor=4, and=0x1F)
#define SWZ_XOR4(v) __int_as_float(__builtin_amdgcn_ds_swizzle(__float_as_int(v), 0x101F))

// x (B, D, K) -> xt[(b*K+k)*D + t] = x[b][t][k]
__global__ __launch_bounds__(256) void transpose_x(const float* __restrict__ x,
                                                   float* __restrict__ xt) {
  __shared__ float tile[32][33];
  int b = blockIdx.x, t0 = blockIdx.y * 32, k0 = blockIdx.z * 32;
  int tx = threadIdx.x, ty = threadIdx.y;
#pragma unroll
  for (int i = 0; i < 32; i += 8) {
    int t = t0 + ty + i, k = k0 + tx;
    tile[ty + i][tx] = (t < DD && k < KK) ? x[((size_t)b * DD + t) * KK + k] : 0.0f;
  }
  __syncthreads();
#pragma unroll
  for (int i = 0; i < 32; i += 8) {
    int k = k0 + ty + i, t = t0 + tx;
    if (k < KK && t < DD) xt[((size_t)b * KK + k) * DD + t] = tile[tx][ty + i];
  }
}

// first zero index (else D) per sequence + length histogram
__global__ __launch_bounds__(64) void compute_lengths(const float* __restrict__ xt,
                                                      int* __restrict__ lengths,
                                                      int* __restrict__ hist) {
  int n = blockIdx.x, lane = threadIdx.x;
  int m = DD;
  for (int t = lane; t < DD; t += 64) {
    if (xt[(size_t)n * DD + t] == 0.0f) { m = t; break; }
  }
#pragma unroll
  for (int off = 1; off < 64; off <<= 1) {
    int o = __shfl_xor(m, off, 64);
    m = (o < m) ? o : m;
  }
  if (lane == 0) {
    lengths[n] = m;
    atomicAdd(&hist[m], 1);
  }
}

// wave-parallel exclusive prefix scan over 512 bins (8 bins/lane + shfl scan)
__global__ __launch_bounds__(64) void scan_offsets(const int* __restrict__ hist,
                                                   int* __restrict__ offs) {
  int lane = threadIdx.x;
  int v[8], tot = 0;
#pragma unroll
  for (int i = 0; i < 8; ++i) { v[i] = tot; tot += hist[lane * 8 + i]; }
  int incl = tot;
#pragma unroll
  for (int off = 1; off < 64; off <<= 1) {
    int oth = __shfl_up(incl, off, 64);
    if (lane >= off) incl += oth;
  }
  int excl = incl - tot;
#pragma unroll
  for (int i = 0; i < 8; ++i) offs[lane * 8 + i] = excl + v[i];
}

__global__ __launch_bounds__(256) void scatter_sort(const int* __restrict__ lengths,
                                                    int* __restrict__ offs,
                                                    int* __restrict__ order,
                                                    int* __restrict__ len_sorted) {
  int n = blockIdx.x * 256 + threadIdx.x;
  if (n >= NN) return;
  int len = lengths[n];
  int pos = atomicAdd(&offs[len], 1);
  order[pos] = n;
  len_sorted[pos] = len;
}

// 8 lanes per (sorted-seq, dir); lane li owns hidden unit li.
// Work balance: physical wave p takes sorted wave-octet p/2 (even) or W-1-p/2 (odd)
// -> every block holds 2 short + 2 long waves; uniform length within each octet.
// h-exchange: 1 ds_swizzle (issued end of prev step) + 8 quad_perm DPP.
// Math packed as float2 -> v_pk_fma_f32. x stream: 4-step register prefetch.
template <int IN_DIM, bool IND_IN, bool WRITE_SEQ, bool FWD_ONLY>
__global__ __launch_bounds__(256) void gru_scan(
    const float* __restrict__ in, float* __restrict__ out, float* __restrict__ feat,
    const int* __restrict__ len_sorted, const int* __restrict__ order,
    const float* __restrict__ Wih, const float* __restrict__ Whh,
    const float* __restrict__ bih, const float* __restrict__ bhh, int nseq) {
  int p = (blockIdx.x * 256 + threadIdx.x) >> 6;  // physical wave
  int lane = threadIdx.x & 63;
  int G = FWD_ONLY ? nseq : nseq * 2;
  int W = (G + 7) >> 3;
  if (p >= W) return;
  int o = (p & 1) ? (W - 1 - (p >> 1)) : (p >> 1);
  int gidx = o * 8 + (lane >> 3);   // uniform across each 8-lane group
  int li = lane & 7;
  if (gidx >= G) return;
  int sg  = FWD_ONLY ? gidx : (gidx >> 1);
  int dir = FWD_ONLY ? 0 : (gidx & 1);
  int len = len_sorted[sg];

  int qb = li & 4, qbx = qb ^ 4;
  f2 wAB[3][4];       // {wA, wB} pairs for packed gh
  f2 wi2[3][8];
  float wi1[3];
  float bs[3], bh2;   // bs[0..1] = bih+bhh (foldable), bs[2] = bih; bh2 = bhh n-gate
#pragma unroll
  for (int gt = 0; gt < 3; ++gt) {
    int row = dir * 24 + gt * 8 + li;
    if constexpr (IN_DIM == 16) {
      const f2* wp = reinterpret_cast<const f2*>(Wih + row * 16);
#pragma unroll
      for (int q = 0; q < 8; ++q) wi2[gt][q] = wp[q];
    } else {
      wi1[gt] = Wih[row];
    }
#pragma unroll
    for (int P = 0; P < 4; ++P) {
      f2 w; w.x = Whh[row * 8 + qb + P]; w.y = Whh[row * 8 + qbx + P];
      wAB[gt][P] = w;
    }
    bs[gt] = bih[row] + ((gt < 2) ? bhh[row] : 0.0f);
    if (gt == 2) bh2 = bhh[row];
  }

  int steps = len;  // >= 200 always
  float h = 0.0f, hx = 0.0f;  // hx = swizzled h from end of previous step
  const float* basep = IND_IN ? (in + (size_t)order[sg] * DD)
                              : (in + (size_t)sg * DD * IN_DIM);
  const float* px = basep + (size_t)((dir == 0) ? 0 : (len - 1)) * IN_DIM;
  ptrdiff_t xstep = (dir == 0) ? IN_DIM : -IN_DIM;

  float* pw = nullptr; ptrdiff_t wstep = 0;
  if constexpr (WRITE_SEQ) {
    pw = out + ((size_t)sg * DD + ((dir == 0) ? 0 : (len - 1))) * 16 + dir * 8 + li;
    wstep = (dir == 0) ? 16 : -16;
  }

  // shared epilogue: gh (packed), activations, h update, next-step swizzle, store
  auto core = [&](float a0, float a1, float a2) {
    float hq0 = QPERM(h, 0), hq1 = QPERM(h, 1), hq2 = QPERM(h, 2), hq3 = QPERM(h, 3);
    float hx0 = QPERM(hx, 0), hx1 = QPERM(hx, 1), hx2 = QPERM(hx, 2), hx3 = QPERM(hx, 3);
    f2 u0; u0.x = hq0; u0.y = hx0;
    f2 u1; u1.x = hq1; u1.y = hx1;
    f2 u2; u2.x = hq2; u2.y = hx2;
    f2 u3; u3.x = hq3; u3.y = hx3;

    f2 c0 = wAB[0][0] * u0; c0 += wAB[0][1] * u1; c0 += wAB[0][2] * u2; c0 += wAB[0][3] * u3;
    f2 c1 = wAB[1][0] * u0; c1 += wAB[1][1] * u1; c1 += wAB[1][2] * u2; c1 += wAB[1][3] * u3;
    f2 c2; c2.x = bh2; c2.y = 0.0f;
    c2 += wAB[2][0] * u0; c2 += wAB[2][1] * u1; c2 += wAB[2][2] * u2; c2 += wAB[2][3] * u3;

    float r = fast_sigmoid(a0 + c0.x + c0.y);
    float z = fast_sigmoid(a1 + c1.x + c1.y);
    float n = fast_tanh(a2 + r * (c2.x + c2.y));
    h = z * (h - n) + n;  // == (1-z)*n + z*h
    hx = SWZ_XOR4(h);     // issue now; consumed next step (LDS latency hidden)
    if constexpr (WRITE_SEQ) { *pw = h; pw += wstep; }
  };

  if constexpr (IN_DIM == 1) {
    float s0_, s1_, s2_, s3_;
    auto ld = [&](float& S_) { S_ = *px; px += xstep; };
    auto st = [&](float& S_, bool pf) {
      float a0 = fmaf(wi1[0], S_, bs[0]);
      float a1 = fmaf(wi1[1], S_, bs[1]);
      float a2 = fmaf(wi1[2], S_, bs[2]);
      if (pf) ld(S_);
      core(a0, a1, a2);
    };
    ld(s0_); ld(s1_); ld(s2_); ld(s3_);
    int t = 0;
    for (; t + 4 <= steps; t += 4) {
      st(s0_, true); st(s1_, true); st(s2_, true); st(s3_, true);
    }
    int rem = steps - t;
    if (rem > 0) st(s0_, false);
    if (rem > 1) st(s1_, false);
    if (rem > 2) st(s2_, false);
  } else {
    float4 b0_[4], b1_[4], b2_[4], b3_[4];
    auto ld = [&](float4 (&B_)[4]) {
      const float4* q4 = reinterpret_cast<const float4*>(px);
      B_[0] = q4[0]; B_[1] = q4[1]; B_[2] = q4[2]; B_[3] = q4[3];
      px += xstep;
    };
    auto st = [&](float4 (&B_)[4], bool pf) {
      f2 A0; A0.x = bs[0]; A0.y = 0.0f;
      f2 A1; A1.x = bs[1]; A1.y = 0.0f;
      f2 A2; A2.x = bs[2]; A2.y = 0.0f;
#pragma unroll
      for (int q = 0; q < 4; ++q) {
        f2 lo;  lo.x  = B_[q].x; lo.y  = B_[q].y;
        f2 hi2; hi2.x = B_[q].z; hi2.y = B_[q].w;
        A0 += wi2[0][2*q] * lo; A0 += wi2[0][2*q+1] * hi2;
        A1 += wi2[1][2*q] * lo; A1 += wi2[1][2*q+1] * hi2;
        A2 += wi2[2][2*q] * lo; A2 += wi2[2][2*q+1] * hi2;
      }
      if (pf) ld(B_);
      core(A0.x + A0.y, A1.x + A1.y, A2.x + A2.y);
    };
    ld(b0_); ld(b1_); ld(b2_); ld(b3_);
    int t = 0;
    for (; t + 4 <= steps; t += 4) {
      st(b0_, true); st(b1_, true); st(b2_, true); st(b3_, true);
    }
    int rem = steps - t;
    if (rem > 0) st(b0_, false);
    if (rem > 1) st(b1_, false);
    if (rem > 2) st(b2_, false);
  }

  if constexpr (!WRITE_SEQ) {
    feat[(size_t)order[sg] * 16 + dir * 8 + li] = h;
  }
}

// last layer, bwd direction: only t = len-1 matters and h0 = 0 => gh = bhh (closed form)
__global__ __launch_bounds__(256) void bwd_last(
    const float* __restrict__ in, float* __restrict__ feat,
    const int* __restrict__ len_sorted, const int* __restrict__ order,
    const float* __restrict__ Wih, const float* __restrict__ bih,
    const float* __restrict__ bhh, int nseq) {
  int tid = blockIdx.x * blockDim.x + threadIdx.x;
  int sg = tid >> 3, li = tid & 7;
  if (sg >= nseq) return;
  int len = len_sorted[sg];
  const float4* xp = reinterpret_cast<const float4*>(in + ((size_t)sg * DD + (len - 1)) * 16);
  float4 x0 = xp[0], x1 = xp[1], x2 = xp[2], x3 = xp[3];
  float a[3], bh[3];
#pragma unroll
  for (int gt = 0; gt < 3; ++gt) {
    int row = 24 + gt * 8 + li;  // dir=1 rows
    const float* wp = Wih + row * 16;
    float acc = bih[row];
    acc = fmaf(wp[0], x0.x, fmaf(wp[1], x0.y, fmaf(wp[2], x0.z, fmaf(wp[3], x0.w, acc))));
    acc = fmaf(wp[4], x1.x, fmaf(wp[5], x1.y, fmaf(wp[6], x1.z, fmaf(wp[7], x1.w, acc))));
    acc = fmaf(wp[8], x2.x, fmaf(wp[9], x2.y, fmaf(wp[10], x2.z, fmaf(wp[11], x2.w, acc))));
    acc = fmaf(wp[12], x3.x, fmaf(wp[13], x3.y, fmaf(wp[14], x3.z, fmaf(wp[15], x3.w, acc))));
    a[gt] = acc;
    bh[gt] = bhh[row];
  }
  float r = fast_sigmoid(a[0] + bh[0]);
  float z = fast_sigmoid(a[1] + bh[1]);
  float n = fast_tanh(a[2] + r * bh[2]);
  float h = (1.0f - z) * n;
  feat[(size_t)order[sg] * 16 + 8 + li] = h;
}

__global__ __launch_bounds__(256) void head_kernel(
    const float* __restrict__ feat, const float* __restrict__ w1,
    const float* __restrict__ b1, const float* __restrict__ w2,
    const float* __restrict__ b2, float* __restrict__ out) {
  int n = blockIdx.x * blockDim.x + threadIdx.x;
  if (n >= NN) return;
  float f[16];
  const float4* p = reinterpret_cast<const float4*>(feat + (size_t)n * 16);
#pragma unroll
  for (int q = 0; q < 4; ++q) {
    float4 v = p[q];
    f[4*q] = v.x; f[4*q+1] = v.y; f[4*q+2] = v.z; f[4*q+3] = v.w;
  }
  float y[8];
#pragma unroll
  for (int o = 0; o < 8; ++o) {
    float s = b1[o];
#pragma unroll
    for (int j = 0; j < 16; ++j) s += f[j] * w1[o * 16 + j];
    y[o] = (s > 0.0f) ? s : 0.2f * s;
  }
#pragma unroll
  for (int o2 = 0; o2 < 8; ++o2) {
    float s = b2[o2];
#pragma unroll
    for (int o = 0; o < 8; ++o) s += y[o] * w2[o2 * 8 + o];
    out[(size_t)n * 8 + o2] = s;
  }
}

extern "C" void kernel_launch(void* const* d_in, const int* in_sizes, int n_in,
                              void* d_out, int out_size, void* d_ws, size_t ws_size,
                              hipStream_t stream) {
  const float* x      = (const float*)d_in[0];
  const float* w_ih0  = (const float*)d_in[1];
  const float* w_hh0  = (const float*)d_in[2];
  const float* b_ih0  = (const float*)d_in[3];
  const float* b_hh0  = (const float*)d_in[4];
  const float* w_ih   = (const float*)d_in[5];
  const float* w_hh   = (const float*)d_in[6];
  const float* b_ih   = (const float*)d_in[7];
  const float* b_hh   = (const float*)d_in[8];
  const float* lin1_w = (const float*)d_in[9];
  const float* lin1_b = (const float*)d_in[10];
  const float* lin2_w = (const float*)d_in[11];
  const float* lin2_b = (const float*)d_in[12];
  float* out = (float*)d_out;

  char* ws = (char*)d_ws;
  size_t off = 0;
  auto alloc = [&](size_t bytes) -> void* {
    void* p = ws + off;
    off += (bytes + 255) & ~(size_t)255;
    return p;
  };
  alloc(1024);  // front guard (backward prefetch overrun)
  float* xt         = (float*)alloc((size_t)NN * DD * sizeof(float) + 1024);
  int*   lengths    = (int*)  alloc((size_t)NN * sizeof(int));
  int*   hist       = (int*)  alloc(NBINS * sizeof(int));
  int*   offs       = (int*)  alloc(NBINS * sizeof(int));
  int*   order      = (int*)  alloc((size_t)NN * sizeof(int));
  int*   len_sorted = (int*)  alloc((size_t)NN * sizeof(int));
  float* feat       = (float*)alloc((size_t)NN * 16 * sizeof(float));
  size_t base = off;
  size_t per_seq = (size_t)DD * 16 * sizeof(float) * 2 + 1024;
  int Nc = NN;
  if (base + (size_t)NN * per_seq + 8192 > ws_size) {
    size_t avail = (ws_size > base + 8192) ? (ws_size - base - 8192) : 0;
    size_t nc = avail / per_seq;
    if (nc < 1) nc = 1;
    if (nc > (size_t)NN) nc = NN;
    Nc = (int)nc;
  }
  alloc(1024);  // guard before bufA
  float* bufA = (float*)alloc((size_t)Nc * DD * 16 * sizeof(float) + 1024);
  float* bufB = (float*)alloc((size_t)Nc * DD * 16 * sizeof(float) + 1024);

  hipMemsetAsync(hist, 0, NBINS * sizeof(int), stream);
  dim3 gT(BB, (DD + 31) / 32, (KK + 31) / 32), bT(32, 8, 1);
  hipLaunchKernelGGL(transpose_x, gT, bT, 0, stream, x, xt);
  hipLaunchKernelGGL(compute_lengths, dim3(NN), dim3(64), 0, stream, xt, lengths, hist);
  hipLaunchKernelGGL(scan_offsets, dim3(1), dim3(64), 0, stream, hist, offs);
  hipLaunchKernelGGL(scatter_sort, dim3((NN + 255) / 256), dim3(256), 0, stream,
                     lengths, offs, order, len_sorted);

  for (int s0 = 0; s0 < NN; s0 += Nc) {
    int ns = (NN - s0 < Nc) ? (NN - s0) : Nc;
    int W2 = (ns * 2 + 7) / 8;           // bidir wave count
    int W1 = (ns + 7) / 8;               // fwd-only wave count
    int blk2 = (W2 + 3) / 4;
    int blk1f = (W1 + 3) / 4;
    int blk1 = (ns * 8 + 255) / 256;     // bwd_last
    gru_scan<1, true, true, false><<<blk2, 256, 0, stream>>>(
        xt, bufA, nullptr, len_sorted + s0, order + s0,
        w_ih0, w_hh0, b_ih0, b_hh0, ns);
    gru_scan<16, false, true, false><<<blk2, 256, 0, stream>>>(
        bufA, bufB, nullptr, len_sorted + s0, order + s0,
        w_ih + 0 * 2 * 24 * 16, w_hh + 0 * 2 * 24 * 8,
        b_ih + 0 * 2 * 24, b_hh + 0 * 2 * 24, ns);
    gru_scan<16, false, true, false><<<blk2, 256, 0, stream>>>(
        bufB, bufA, nullptr, len_sorted + s0, order + s0,
        w_ih + 1 * 2 * 24 * 16, w_hh + 1 * 2 * 24 * 8,
        b_ih + 1 * 2 * 24, b_hh + 1 * 2 * 24, ns);
    gru_scan<16, false, false, true><<<blk1f, 256, 0, stream>>>(
        bufA, nullptr, feat, len_sorted + s0, order + s0,
        w_ih + 2 * 2 * 24 * 16, w_hh + 2 * 2 * 24 * 8,
        b_ih + 2 * 2 * 24, b_hh + 2 * 2 * 24, ns);
    hipLaunchKernelGGL(bwd_last, dim3(blk1), dim3(256), 0, stream,
                       bufA, feat, len_sorted + s0, order + s0,
                       w_ih + 2 * 2 * 24 * 16, b_ih + 2 * 2 * 24, b_hh + 2 * 2 * 24, ns);
  }
  hipLaunchKernelGGL(head_kernel, dim3((NN + 255) / 256), dim3(256), 0, stream,
                     feat, lin1_w, lin1_b, lin2_w, lin2_b, out);
}

// Round 7
// 457.261 us; speedup vs baseline: 3.1749x; 1.8267x over previous
//
#include <hip/hip_runtime.h>

#define BB 32
#define DD 400
#define KK 200
#define NN (BB*KK)
#define NBINS 512

typedef float f2 __attribute__((ext_vector_type(2)));
typedef _Float16 half_t;
typedef _Float16 f16x2 __attribute__((ext_vector_type(2)));

#if defined(__has_builtin)
#if __has_builtin(__builtin_amdgcn_fdot2)
#define HAVE_FDOT2 1
#endif
#endif

__device__ __forceinline__ float dot2(f16x2 w, f16x2 v, float acc) {
#ifdef HAVE_FDOT2
  return __builtin_amdgcn_fdot2(w, v, acc, false);
#else
  return fmaf((float)w.x, (float)v.x, fmaf((float)w.y, (float)v.y, acc));
#endif
}

__device__ __forceinline__ float fast_sigmoid(float x) {
  float e = __builtin_amdgcn_exp2f(-1.4426950408889634f * x);
  return __builtin_amdgcn_rcpf(1.0f + e);
}
__device__ __forceinline__ float fast_tanh(float x) {
  float e = __builtin_amdgcn_exp2f(-2.8853900817779268f * x);
  return 2.0f * __builtin_amdgcn_rcpf(1.0f + e) - 1.0f;
}

// quad_perm broadcast P within each aligned 4-lane quad (VALU pipe, no LDS)
#define QPERM(v, P) __int_as_float(__builtin_amdgcn_mov_dpp(__float_as_int(v), (P)*0x55, 0xF, 0xF, true))
// lane ^ 4 exchange (BitMode swizzle: xor=4, and=0x1F)
#define SWZ_XOR4(v) __int_as_float(__builtin_amdgcn_ds_swizzle(__float_as_int(v), 0x101F))

// x (B, D, K) -> xt[(b*K+k)*D + t] = x[b][t][k]
__global__ __launch_bounds__(256) void transpose_x(const float* __restrict__ x,
                                                   float* __restrict__ xt) {
  __shared__ float tile[32][33];
  int b = blockIdx.x, t0 = blockIdx.y * 32, k0 = blockIdx.z * 32;
  int tx = threadIdx.x, ty = threadIdx.y;
#pragma unroll
  for (int i = 0; i < 32; i += 8) {
    int t = t0 + ty + i, k = k0 + tx;
    tile[ty + i][tx] = (t < DD && k < KK) ? x[((size_t)b * DD + t) * KK + k] : 0.0f;
  }
  __syncthreads();
#pragma unroll
  for (int i = 0; i < 32; i += 8) {
    int k = k0 + ty + i, t = t0 + tx;
    if (k < KK && t < DD) xt[((size_t)b * KK + k) * DD + t] = tile[tx][ty + i];
  }
}

// first zero index (else D) per sequence + length histogram
__global__ __launch_bounds__(64) void compute_lengths(const float* __restrict__ xt,
                                                      int* __restrict__ lengths,
                                                      int* __restrict__ hist) {
  int n = blockIdx.x, lane = threadIdx.x;
  int m = DD;
  for (int t = lane; t < DD; t += 64) {
    if (xt[(size_t)n * DD + t] == 0.0f) { m = t; break; }
  }
#pragma unroll
  for (int off = 1; off < 64; off <<= 1) {
    int o = __shfl_xor(m, off, 64);
    m = (o < m) ? o : m;
  }
  if (lane == 0) {
    lengths[n] = m;
    atomicAdd(&hist[m], 1);
  }
}

// wave-parallel exclusive prefix scan over 512 bins (8 bins/lane + shfl scan)
__global__ __launch_bounds__(64) void scan_offsets(const int* __restrict__ hist,
                                                   int* __restrict__ offs) {
  int lane = threadIdx.x;
  int v[8], tot = 0;
#pragma unroll
  for (int i = 0; i < 8; ++i) { v[i] = tot; tot += hist[lane * 8 + i]; }
  int incl = tot;
#pragma unroll
  for (int off = 1; off < 64; off <<= 1) {
    int oth = __shfl_up(incl, off, 64);
    if (lane >= off) incl += oth;
  }
  int excl = incl - tot;
#pragma unroll
  for (int i = 0; i < 8; ++i) offs[lane * 8 + i] = excl + v[i];
}

__global__ __launch_bounds__(256) void scatter_sort(const int* __restrict__ lengths,
                                                    int* __restrict__ offs,
                                                    int* __restrict__ order,
                                                    int* __restrict__ len_sorted) {
  int n = blockIdx.x * 256 + threadIdx.x;
  if (n >= NN) return;
  int len = lengths[n];
  int pos = atomicAdd(&offs[len], 1);
  order[pos] = n;
  len_sorted[pos] = len;
}

// 8 lanes per (sorted-seq, dir); lane li owns hidden unit li.
// Work balance: physical wave p takes sorted wave-octet p/2 (even) or W-1-p/2 (odd).
// h-exchange: 1 ds_swizzle (issued end of prev step) + 8 quad_perm DPP.
// Inter-layer streams are f16; gi dots via v_dot2_f32_f16 (f32 accumulate).
// IN_DIM==1: f32 input (layer 0). x stream: 4-step register prefetch.
template <int IN_DIM, bool IND_IN, bool WRITE_SEQ, bool FWD_ONLY>
__global__ __launch_bounds__(256) void gru_scan(
    const void* __restrict__ in, half_t* __restrict__ out, float* __restrict__ feat,
    const int* __restrict__ len_sorted, const int* __restrict__ order,
    const float* __restrict__ Wih, const float* __restrict__ Whh,
    const float* __restrict__ bih, const float* __restrict__ bhh, int nseq) {
  int p = (blockIdx.x * 256 + threadIdx.x) >> 6;  // physical wave
  int lane = threadIdx.x & 63;
  int G = FWD_ONLY ? nseq : nseq * 2;
  int W = (G + 7) >> 3;
  if (p >= W) return;
  int o = (p & 1) ? (W - 1 - (p >> 1)) : (p >> 1);
  int gidx = o * 8 + (lane >> 3);
  int li = lane & 7;
  if (gidx >= G) return;
  int sg  = FWD_ONLY ? gidx : (gidx >> 1);
  int dir = FWD_ONLY ? 0 : (gidx & 1);
  int len = len_sorted[sg];

  int qb = li & 4, qbx = qb ^ 4;
  f2 wAB[3][4];       // {wA, wB} pairs for packed gh
  f16x2 wi2[3][8];
  float wi1[3];
  float bs[3], bh2;   // bs[0..1] = bih+bhh, bs[2] = bih; bh2 = bhh n-gate
#pragma unroll
  for (int gt = 0; gt < 3; ++gt) {
    int row = dir * 24 + gt * 8 + li;
    if constexpr (IN_DIM == 16) {
#pragma unroll
      for (int q = 0; q < 8; ++q) {
        f16x2 w;
        w.x = (half_t)Wih[row * 16 + 2 * q];
        w.y = (half_t)Wih[row * 16 + 2 * q + 1];
        wi2[gt][q] = w;
      }
    } else {
      wi1[gt] = Wih[row];
    }
#pragma unroll
    for (int P = 0; P < 4; ++P) {
      f2 w; w.x = Whh[row * 8 + qb + P]; w.y = Whh[row * 8 + qbx + P];
      wAB[gt][P] = w;
    }
    bs[gt] = bih[row] + ((gt < 2) ? bhh[row] : 0.0f);
    if (gt == 2) bh2 = bhh[row];
  }

  int steps = len;  // >= 200 always
  float h = 0.0f, hx = 0.0f;

  const float* px = nullptr;
  const half_t* pxh = nullptr;
  ptrdiff_t xstep;
  if constexpr (IN_DIM == 1) {
    const float* basep = (const float*)in + (IND_IN ? (size_t)order[sg] * DD : (size_t)sg * DD);
    px = basep + ((dir == 0) ? 0 : (len - 1));
    xstep = (dir == 0) ? 1 : -1;
  } else {
    const half_t* basep = (const half_t*)in + (size_t)sg * DD * 16;
    pxh = basep + (size_t)((dir == 0) ? 0 : (len - 1)) * 16;
    xstep = (dir == 0) ? 16 : -16;
  }

  half_t* pw = nullptr; ptrdiff_t wstep = 0;
  if constexpr (WRITE_SEQ) {
    pw = out + ((size_t)sg * DD + ((dir == 0) ? 0 : (len - 1))) * 16 + dir * 8 + li;
    wstep = (dir == 0) ? 16 : -16;
  }

  // shared epilogue: gh (packed f32), activations, h update, next-step swizzle, store
  auto core = [&](float a0, float a1, float a2) {
    float hq0 = QPERM(h, 0), hq1 = QPERM(h, 1), hq2 = QPERM(h, 2), hq3 = QPERM(h, 3);
    float hx0 = QPERM(hx, 0), hx1 = QPERM(hx, 1), hx2 = QPERM(hx, 2), hx3 = QPERM(hx, 3);
    f2 u0; u0.x = hq0; u0.y = hx0;
    f2 u1; u1.x = hq1; u1.y = hx1;
    f2 u2; u2.x = hq2; u2.y = hx2;
    f2 u3; u3.x = hq3; u3.y = hx3;

    f2 c0 = wAB[0][0] * u0; c0 += wAB[0][1] * u1; c0 += wAB[0][2] * u2; c0 += wAB[0][3] * u3;
    f2 c1 = wAB[1][0] * u0; c1 += wAB[1][1] * u1; c1 += wAB[1][2] * u2; c1 += wAB[1][3] * u3;
    f2 c2; c2.x = bh2; c2.y = 0.0f;
    c2 += wAB[2][0] * u0; c2 += wAB[2][1] * u1; c2 += wAB[2][2] * u2; c2 += wAB[2][3] * u3;

    float r = fast_sigmoid(a0 + c0.x + c0.y);
    float z = fast_sigmoid(a1 + c1.x + c1.y);
    float n = fast_tanh(a2 + r * (c2.x + c2.y));
    h = z * (h - n) + n;  // == (1-z)*n + z*h
    hx = SWZ_XOR4(h);     // issue now; consumed next step (LDS latency hidden)
    if constexpr (WRITE_SEQ) { *pw = (half_t)h; pw += wstep; }
  };

  if constexpr (IN_DIM == 1) {
    float s0_, s1_, s2_, s3_;
    auto ld = [&](float& S_) { S_ = *px; px += xstep; };
    auto st = [&](float& S_, bool pf) {
      float a0 = fmaf(wi1[0], S_, bs[0]);
      float a1 = fmaf(wi1[1], S_, bs[1]);
      float a2 = fmaf(wi1[2], S_, bs[2]);
      if (pf) ld(S_);
      core(a0, a1, a2);
    };
    ld(s0_); ld(s1_); ld(s2_); ld(s3_);
    int t = 0;
    for (; t + 4 <= steps; t += 4) {
      st(s0_, true); st(s1_, true); st(s2_, true); st(s3_, true);
    }
    int rem = steps - t;
    if (rem > 0) st(s0_, false);
    if (rem > 1) st(s1_, false);
    if (rem > 2) st(s2_, false);
  } else {
    uint4 b0_[2], b1_[2], b2_[2], b3_[2];
    auto ld = [&](uint4 (&B_)[2]) {
      const uint4* q4 = reinterpret_cast<const uint4*>(pxh);
      B_[0] = q4[0]; B_[1] = q4[1];
      pxh += xstep;
    };
    auto st = [&](uint4 (&B_)[2], bool pf) {
      float a0 = bs[0], a1 = bs[1], a2 = bs[2];
#pragma unroll
      for (int q = 0; q < 2; ++q) {
        f16x2 p0 = __builtin_bit_cast(f16x2, B_[q].x);
        f16x2 p1 = __builtin_bit_cast(f16x2, B_[q].y);
        f16x2 p2 = __builtin_bit_cast(f16x2, B_[q].z);
        f16x2 p3 = __builtin_bit_cast(f16x2, B_[q].w);
        a0 = dot2(wi2[0][4*q], p0, a0); a0 = dot2(wi2[0][4*q+1], p1, a0);
        a0 = dot2(wi2[0][4*q+2], p2, a0); a0 = dot2(wi2[0][4*q+3], p3, a0);
        a1 = dot2(wi2[1][4*q], p0, a1); a1 = dot2(wi2[1][4*q+1], p1, a1);
        a1 = dot2(wi2[1][4*q+2], p2, a1); a1 = dot2(wi2[1][4*q+3], p3, a1);
        a2 = dot2(wi2[2][4*q], p0, a2); a2 = dot2(wi2[2][4*q+1], p1, a2);
        a2 = dot2(wi2[2][4*q+2], p2, a2); a2 = dot2(wi2[2][4*q+3], p3, a2);
      }
      if (pf) ld(B_);
      core(a0, a1, a2);
    };
    ld(b0_); ld(b1_); ld(b2_); ld(b3_);
    int t = 0;
    for (; t + 4 <= steps; t += 4) {
      st(b0_, true); st(b1_, true); st(b2_, true); st(b3_, true);
    }
    int rem = steps - t;
    if (rem > 0) st(b0_, false);
    if (rem > 1) st(b1_, false);
    if (rem > 2) st(b2_, false);
  }

  if constexpr (!WRITE_SEQ) {
    feat[(size_t)order[sg] * 16 + dir * 8 + li] = h;
  }
}

// last layer, bwd direction: only t = len-1 matters and h0 = 0 => gh = bhh (closed form)
__global__ __launch_bounds__(256) void bwd_last(
    const half_t* __restrict__ in, float* __restrict__ feat,
    const int* __restrict__ len_sorted, const int* __restrict__ order,
    const float* __restrict__ Wih, const float* __restrict__ bih,
    const float* __restrict__ bhh, int nseq) {
  int tid = blockIdx.x * blockDim.x + threadIdx.x;
  int sg = tid >> 3, li = tid & 7;
  if (sg >= nseq) return;
  int len = len_sorted[sg];
  const half_t* xp = in + ((size_t)sg * DD + (len - 1)) * 16;
  float xv[16];
#pragma unroll
  for (int j = 0; j < 16; ++j) xv[j] = (float)xp[j];
  float a[3], bh[3];
#pragma unroll
  for (int gt = 0; gt < 3; ++gt) {
    int row = 24 + gt * 8 + li;  // dir=1 rows
    const float* wp = Wih + row * 16;
    float acc = bih[row];
#pragma unroll
    for (int j = 0; j < 16; ++j) acc = fmaf(wp[j], xv[j], acc);
    a[gt] = acc;
    bh[gt] = bhh[row];
  }
  float r = fast_sigmoid(a[0] + bh[0]);
  float z = fast_sigmoid(a[1] + bh[1]);
  float n = fast_tanh(a[2] + r * bh[2]);
  float h = (1.0f - z) * n;
  feat[(size_t)order[sg] * 16 + 8 + li] = h;
}

__global__ __launch_bounds__(256) void head_kernel(
    const float* __restrict__ feat, const float* __restrict__ w1,
    const float* __restrict__ b1, const float* __restrict__ w2,
    const float* __restrict__ b2, float* __restrict__ out) {
  int n = blockIdx.x * blockDim.x + threadIdx.x;
  if (n >= NN) return;
  float f[16];
  const float4* p = reinterpret_cast<const float4*>(feat + (size_t)n * 16);
#pragma unroll
  for (int q = 0; q < 4; ++q) {
    float4 v = p[q];
    f[4*q] = v.x; f[4*q+1] = v.y; f[4*q+2] = v.z; f[4*q+3] = v.w;
  }
  float y[8];
#pragma unroll
  for (int o = 0; o < 8; ++o) {
    float s = b1[o];
#pragma unroll
    for (int j = 0; j < 16; ++j) s += f[j] * w1[o * 16 + j];
    y[o] = (s > 0.0f) ? s : 0.2f * s;
  }
#pragma unroll
  for (int o2 = 0; o2 < 8; ++o2) {
    float s = b2[o2];
#pragma unroll
    for (int o = 0; o < 8; ++o) s += y[o] * w2[o2 * 8 + o];
    out[(size_t)n * 8 + o2] = s;
  }
}

extern "C" void kernel_launch(void* const* d_in, const int* in_sizes, int n_in,
                              void* d_out, int out_size, void* d_ws, size_t ws_size,
                              hipStream_t stream) {
  const float* x      = (const float*)d_in[0];
  const float* w_ih0  = (const float*)d_in[1];
  const float* w_hh0  = (const float*)d_in[2];
  const float* b_ih0  = (const float*)d_in[3];
  const float* b_hh0  = (const float*)d_in[4];
  const float* w_ih   = (const float*)d_in[5];
  const float* w_hh   = (const float*)d_in[6];
  const float* b_ih   = (const float*)d_in[7];
  const float* b_hh   = (const float*)d_in[8];
  const float* lin1_w = (const float*)d_in[9];
  const float* lin1_b = (const float*)d_in[10];
  const float* lin2_w = (const float*)d_in[11];
  const float* lin2_b = (const float*)d_in[12];
  float* out = (float*)d_out;

  char* ws = (char*)d_ws;
  size_t off = 0;
  auto alloc = [&](size_t bytes) -> void* {
    void* p = ws + off;
    off += (bytes + 255) & ~(size_t)255;
    return p;
  };
  alloc(1024);  // front guard (backward prefetch overrun)
  float* xt         = (float*)alloc((size_t)NN * DD * sizeof(float) + 1024);
  int*   lengths    = (int*)  alloc((size_t)NN * sizeof(int));
  int*   hist       = (int*)  alloc(NBINS * sizeof(int));
  int*   offs       = (int*)  alloc(NBINS * sizeof(int));
  int*   order      = (int*)  alloc((size_t)NN * sizeof(int));
  int*   len_sorted = (int*)  alloc((size_t)NN * sizeof(int));
  float* feat       = (float*)alloc((size_t)NN * 16 * sizeof(float));
  size_t base = off;
  size_t per_seq = (size_t)DD * 16 * sizeof(half_t) * 2 + 1024;  // two f16 ping-pong buffers
  int Nc = NN;
  if (base + (size_t)NN * per_seq + 8192 > ws_size) {
    size_t avail = (ws_size > base + 8192) ? (ws_size - base - 8192) : 0;
    size_t nc = avail / per_seq;
    if (nc < 1) nc = 1;
    if (nc > (size_t)NN) nc = NN;
    Nc = (int)nc;
  }
  alloc(1024);  // guard before bufA
  half_t* bufA = (half_t*)alloc((size_t)Nc * DD * 16 * sizeof(half_t) + 1024);
  half_t* bufB = (half_t*)alloc((size_t)Nc * DD * 16 * sizeof(half_t) + 1024);

  hipMemsetAsync(hist, 0, NBINS * sizeof(int), stream);
  dim3 gT(BB, (DD + 31) / 32, (KK + 31) / 32), bT(32, 8, 1);
  hipLaunchKernelGGL(transpose_x, gT, bT, 0, stream, x, xt);
  hipLaunchKernelGGL(compute_lengths, dim3(NN), dim3(64), 0, stream, xt, lengths, hist);
  hipLaunchKernelGGL(scan_offsets, dim3(1), dim3(64), 0, stream, hist, offs);
  hipLaunchKernelGGL(scatter_sort, dim3((NN + 255) / 256), dim3(256), 0, stream,
                     lengths, offs, order, len_sorted);

  for (int s0 = 0; s0 < NN; s0 += Nc) {
    int ns = (NN - s0 < Nc) ? (NN - s0) : Nc;
    int W2 = (ns * 2 + 7) / 8;           // bidir wave count
    int W1 = (ns + 7) / 8;               // fwd-only wave count
    int blk2 = (W2 + 3) / 4;
    int blk1f = (W1 + 3) / 4;
    int blk1 = (ns * 8 + 255) / 256;     // bwd_last
    gru_scan<1, true, true, false><<<blk2, 256, 0, stream>>>(
        (const void*)xt, bufA, nullptr, len_sorted + s0, order + s0,
        w_ih0, w_hh0, b_ih0, b_hh0, ns);
    gru_scan<16, false, true, false><<<blk2, 256, 0, stream>>>(
        (const void*)bufA, bufB, nullptr, len_sorted + s0, order + s0,
        w_ih + 0 * 2 * 24 * 16, w_hh + 0 * 2 * 24 * 8,
        b_ih + 0 * 2 * 24, b_hh + 0 * 2 * 24, ns);
    gru_scan<16, false, true, false><<<blk2, 256, 0, stream>>>(
        (const void*)bufB, bufA, nullptr, len_sorted + s0, order + s0,
        w_ih + 1 * 2 * 24 * 16, w_hh + 1 * 2 * 24 * 8,
        b_ih + 1 * 2 * 24, b_hh + 1 * 2 * 24, ns);
    gru_scan<16, false, false, true><<<blk1f, 256, 0, stream>>>(
        (const void*)bufA, nullptr, feat, len_sorted + s0, order + s0,
        w_ih + 2 * 2 * 24 * 16, w_hh + 2 * 2 * 24 * 8,
        b_ih + 2 * 2 * 24, b_hh + 2 * 2 * 24, ns);
    hipLaunchKernelGGL(bwd_last, dim3(blk1), dim3(256), 0, stream,
                       bufA, feat, len_sorted + s0, order + s0,
                       w_ih + 2 * 2 * 24 * 16, b_ih + 2 * 2 * 24, b_hh + 2 * 2 * 24, ns);
  }
  hipLaunchKernelGGL(head_kernel, dim3((NN + 255) / 256), dim3(256), 0, stream,
                     feat, lin1_w, lin1_b, lin2_w, lin2_b, out);
}